// Round 9
// baseline (275.908 us; speedup 1.0000x reference)
//
#include <hip/hip_runtime.h>

typedef unsigned short u16;
typedef __attribute__((ext_vector_type(8))) short s16x8;   // 8 x bf16 frag (verified form)
typedef __attribute__((ext_vector_type(4))) float floatx4;

// xt (per batch): [cg=16][row=66][col=66][c32=32] bf16, spatial-padded NCHW32c
// SWIZZLED: within each 64B (row,col) channel-group, c32 index ^= ((col>>1)&3)<<3
#define XT_ROWELEMS 2112                 // 66*32
#define XT_CGELEMS  139392               // 66*66*32
#define XT_PB       4460544ull           // 16*66*66*32*2 bytes per batch
// wmod (per batch): [t=9][cg=16][o512=512][c32=32] bf16, UNSWIZZLED (A is read
// direct global->VGPR in the MFMA fragment pattern; no LDS, no bank conflicts)
#define WM_ELEMS    2359296ull           // 9*16*512*32 elems per batch
#define WM_PB       4718592ull           // bytes per batch

// async global->LDS DMA, 16B per lane; lds dest = wave-uniform base + lane*16
#define GLDS(gp, lp) __builtin_amdgcn_global_load_lds(                      \
    (const __attribute__((address_space(1))) void*)(gp),                    \
    (__attribute__((address_space(3))) void*)(lp), 16, 0, 0)

__device__ __forceinline__ u16 f2bf(float f) {
  union { float f; unsigned u; } x; x.f = f;
  unsigned r = x.u + 0x7fffu + ((x.u >> 16) & 1u);
  return (u16)(r >> 16);
}

// ---------------- prep unit bodies ----------------
// transpose unit ti in [0, 8192): y = ti&63, cg = (ti>>6)&15, bl = ti>>10. 256 threads.
__device__ __forceinline__ void transpose_unit(
    char* smraw, const float* __restrict__ fm, u16* __restrict__ xt, int ti, int tid)
{
  u16* sm16 = (u16*)smraw;                      // [x=64][ci=32] pad 40
  const int y = ti & 63, cgi = (ti >> 6) & 15, bl = ti >> 10;
  const float* src = fm + (((size_t)bl * 512 + cgi * 32) * 64 + y) * 64;
  const int x4 = (tid & 15) * 4;
#pragma unroll
  for (int it = 0; it < 2; ++it) {
    int ci = (tid >> 4) + it * 16;
    float4 v = *(const float4*)&src[(size_t)ci * 4096 + x4];   // 16B/lane coalesced
    sm16[(x4 + 0) * 40 + ci] = f2bf(v.x);
    sm16[(x4 + 1) * 40 + ci] = f2bf(v.y);
    sm16[(x4 + 2) * 40 + ci] = f2bf(v.z);
    sm16[(x4 + 3) * 40 + ci] = f2bf(v.w);
  }

  u16* cgbase = xt + (size_t)(bl * 16 + cgi) * XT_CGELEMS;
  const uint4 z = {0u, 0u, 0u, 0u};
  u16* rowb = cgbase + (size_t)(y + 1) * XT_ROWELEMS;
  if (tid < 4)              ((uint4*)rowb)[tid] = z;                  // col 0
  else if (tid < 8)         ((uint4*)(rowb + 65 * 32))[tid - 4] = z;  // col 65
  if (y == 0)  for (int i = tid; i < 264; i += 256) ((uint4*)cgbase)[i] = z;
  if (y == 63) for (int i = tid; i < 264; i += 256) ((uint4*)(cgbase + 65 * XT_ROWELEMS))[i] = z;

  __syncthreads();
  const int x = tid >> 2;
  uint4 u = *(const uint4*)&sm16[x * 40 + (tid & 3) * 8];       // one ds_read_b128
  const int col = 1 + x;
  const int slot = (tid & 3) ^ ((col >> 1) & 3);                // pre-swizzle (B path)
  ((uint4*)rowb)[col * 4 + slot] = u;
}

// modulate unit mi in [0, 4096): o = mi&511, bl = mi>>9. 256 threads.
// v3: wmod stored UNSWIZZLED (conv reads A direct from global now).
__device__ __forceinline__ void modulate_unit(
    char* smraw, const float* __restrict__ w, const float* __restrict__ style,
    u16* __restrict__ wm, int mi, int tid)
{
  float* sv = (float*)smraw;                    // 4608 floats
  float* red = (float*)(smraw + 18432);         // 4 floats
  const int o = mi & 511, bl = mi >> 9;
  const float gain = 0.014731391f;              // 1/sqrt(512*9)
  const float* wo = w + (size_t)o * 4608;       // flat idx = ci*9 + t
  const float* st = style + (size_t)bl * 512;
  float ss = 0.f;
#pragma unroll
  for (int j = 0; j < 5; ++j) {                 // 1152 float4 slots over 256 thr
    int s4 = j * 256 + tid;
    if (s4 < 1152) {
      float4 v = *(const float4*)&wo[s4 * 4];   // 16B/lane coalesced
      int i0 = s4 * 4;
      int c0 = i0 / 9, rem = i0 - c0 * 9;       // ci of v.x
      float sa = st[c0];
      float sb = st[c0 < 511 ? c0 + 1 : 511];   // clamp: unused when c0==511
      float w0 = v.x * gain * sa;               // rem+0 < 9 always
      float w1 = v.y * gain * (rem + 1 >= 9 ? sb : sa);
      float w2 = v.z * gain * (rem + 2 >= 9 ? sb : sa);
      float w3 = v.w * gain * (rem + 3 >= 9 ? sb : sa);
      floatx4 wv = {w0, w1, w2, w3};
      ((floatx4*)sv)[s4] = wv;                  // ds_write_b128
      ss += w0 * w0 + w1 * w1 + w2 * w2 + w3 * w3;
    }
  }
#pragma unroll
  for (int off = 32; off > 0; off >>= 1) ss += __shfl_down(ss, off, 64);
  if ((tid & 63) == 0) red[tid >> 6] = ss;
  __syncthreads();
  float sinv = rsqrtf(red[0] + red[1] + red[2] + red[3] + 1e-8f);
  u16* base = wm + (size_t)bl * WM_ELEMS + (size_t)o * 32;
  const int c0 = tid * 2;
  const int pos = c0 & 31;                      // linear (no swizzle)
#pragma unroll
  for (int t = 0; t < 9; ++t) {                 // 9 paired u32 stores
    unsigned lo = f2bf(sv[c0 * 9 + t] * sinv);
    unsigned hi = f2bf(sv[(c0 + 1) * 9 + t] * sinv);
    *(unsigned*)(base + ((size_t)(t * 16 + (c0 >> 5))) * 16384 + pos) = lo | (hi << 16);
  }
}

// ---------------- fused producer dispatch (verified; prep ~24 us, near roofline) ----------------
__global__ __launch_bounds__(256) void prep_fused(
    const float* __restrict__ fm, const float* __restrict__ w,
    const float* __restrict__ style, u16* __restrict__ xt,
    u16* __restrict__ wm, int b0)
{
  __shared__ __align__(16) char smraw[18448];
  const int bid = blockIdx.x;
  const int g = bid / 3, rrole = bid - g * 3;
  const int tid = threadIdx.x;
  if (rrole < 2) {
    const int ti0 = g * 2 + rrole;
    const int y = ti0 & 63, cgi = (ti0 >> 6) & 15, bl = ti0 >> 10;
    transpose_unit(smraw, fm + (size_t)b0 * 512 * 4096,
                   xt, (bl << 10) | (cgi << 6) | y, tid);
  } else {
    const int o = g & 511, bl = g >> 9;
    modulate_unit(smraw, w, style + (size_t)b0 * 512, wm, (bl << 9) | o, tid);
  }
}

// ---------------- conv: implicit-GEMM bf16 MFMA, A direct-to-register ----------------
// 128x128 tile, 128 threads = 2 waves (wave tile 128x64). R8 diagnosis: LDS port
// saturated (~170 KB per CU-step: A GLDS-write + duplicated A reads). Fix: A is
// loaded global->VGPR in fragment pattern (coalesced 1 KB/row-block, unswizzled
// wmod), two-phase: a03 prefetched 1 step ahead, a47 issued at step top and used
// after 16 MFMAs. B stays in LDS (swizzled, conflict-free) but DOUBLE-buffered,
// staged at t==0 with 9 steps of slack -> ONE __syncthreads per cg (16 barriers
// total vs 144+). LDS traffic per CU-step drops ~170 KB -> ~47 KB.
__global__ __launch_bounds__(128, 2) void conv_mfma(
    const u16* __restrict__ Wmod, const u16* __restrict__ xt,
    float* __restrict__ out, int b0, int nb)
{
  const int id = blockIdx.x;
  const int bl = id % nb;                           // same batch -> same XCD (round robin)
  const int rest = id / nb;                         // 0..127
  const int og = rest & 3, p_blk = rest >> 2;       // og: 128-row M chunk; p_blk: 128 px
  const int tid = threadIdx.x;
  const int lane = tid & 63, wave = tid >> 6;       // 2 waves
  const int wn_off = wave * 64;
  const int l15 = lane & 15, quad = lane >> 4;

  __shared__ __align__(16) u16 Bs[2][8448];         // double-buffered B, 2 x 16896 B

  const int y0 = p_blk * 2;
  const size_t xt_base = ((size_t)(bl * 16) * XT_CGELEMS) + (size_t)y0 * XT_ROWELEMS;
  // per-lane A fragment base: row = og*128 + mt*16 + l15, elems quad*8..+7
  const u16* aP = Wmod + (size_t)bl * WM_ELEMS + og * 4096 + l15 * 32 + quad * 8;

  auto stage_b = [&](int cgi, int half) {           // 16896 B contiguous, async
    const char* g = (const char*)(xt + xt_base + (size_t)cgi * XT_CGELEMS);
    char* l = (char*)Bs[half];
    for (int r = wave; r < 16; r += 2)              // 8 GLDS/wave
      GLDS(g + r * 1024 + lane * 16, l + r * 1024);
    if (wave == 0 && lane < 32)                     // 512 B tail
      GLDS(g + 16384 + lane * 16, l + 16384);
  };

  int pr[4], pc[4];
#pragma unroll
  for (int nt = 0; nt < 4; ++nt) {
    int p = wn_off + nt * 16 + l15;                 // 0..127
    pr[nt] = p >> 6; pc[nt] = p & 63;
  }

  floatx4 acc[8][4];
  const floatx4 zf = {0.f, 0.f, 0.f, 0.f};
#pragma unroll
  for (int mt = 0; mt < 8; ++mt)
#pragma unroll
    for (int nt = 0; nt < 4; ++nt) acc[mt][nt] = zf;

  // prologue: a03 for step 0; B(cg0) into half 0
  s16x8 a03[4];
#pragma unroll
  for (int mt = 0; mt < 4; ++mt) a03[mt] = *(const s16x8*)(aP + mt * 512);
  stage_b(0, 0);
  __syncthreads();                                  // full drain: B(0) + a03 visible

#pragma unroll 1
  for (int cg = 0; cg < 16; ++cg) {
    if (cg) __syncthreads();                        // B(cg) writes (9 steps old) + rendezvous
    const u16* Bc = Bs[cg & 1];
#pragma unroll 1
    for (int t = 0; t < 9; ++t) {
      const u16* pS = aP + (size_t)(t * 16 + cg) * 16384;
      s16x8 a47[4];
#pragma unroll
      for (int mt = 0; mt < 4; ++mt)                // issue now, first use after 16 MFMAs
        a47[mt] = *(const s16x8*)(pS + (mt + 4) * 512);
      if (t == 0 && cg < 15) stage_b(cg + 1, (cg + 1) & 1);  // 9 steps of slack

      const int ky = t / 3, kx = t - ky * 3;
      s16x8 bfr[4];
#pragma unroll
      for (int nt = 0; nt < 4; ++nt) {              // B[n][k], swizzled (conflict-free)
        int r = pr[nt] + ky, c = pc[nt] + kx;
        bfr[nt] = *(const s16x8*)&Bc[(r * 66 + c) * 32 + ((quad ^ ((c >> 1) & 3)) << 3)];
      }
#pragma unroll
      for (int mt = 0; mt < 4; ++mt)                // phase 1: mt 0-3 (a03 prefetched)
#pragma unroll
        for (int nt = 0; nt < 4; ++nt)
          acc[mt][nt] = __builtin_amdgcn_mfma_f32_16x16x32_bf16(
              a03[mt], bfr[nt], acc[mt][nt], 0, 0, 0);

      if (!(cg == 15 && t == 8)) {                  // prefetch a03 for step s+1
        const int tn = (t == 8) ? 0 : t + 1;
        const int cgn = (t == 8) ? cg + 1 : cg;
        const u16* pN = aP + (size_t)(tn * 16 + cgn) * 16384;
#pragma unroll
        for (int mt = 0; mt < 4; ++mt)
          a03[mt] = *(const s16x8*)(pN + mt * 512);
      }
#pragma unroll
      for (int mt = 0; mt < 4; ++mt)                // phase 2: mt 4-7 (a47 landed by now)
#pragma unroll
        for (int nt = 0; nt < 4; ++nt)
          acc[mt + 4][nt] = __builtin_amdgcn_mfma_f32_16x16x32_bf16(
              a47[mt], bfr[nt], acc[mt + 4][nt], 0, 0, 0);
    }
  }

  // epilogue: C/D layout col=lane&15, row=quad*4+reg (m89-verified)
  float* outp = out + ((size_t)(b0 + bl) * 512 + og * 128) * 4096 + p_blk * 128;
#pragma unroll
  for (int mt = 0; mt < 8; ++mt)
#pragma unroll
    for (int nt = 0; nt < 4; ++nt) {
      int n = wn_off + nt * 16 + l15;
#pragma unroll
      for (int r = 0; r < 4; ++r) {
        int m = mt * 16 + quad * 4 + r;
        outp[(size_t)m * 4096 + n] = acc[mt][nt][r];
      }
    }
}

// ---------------- fallback: zero-workspace direct conv (known-PASS) ----------------
__global__ __launch_bounds__(256) void conv_direct(
    const float* __restrict__ fm, const float* __restrict__ style,
    const float* __restrict__ w, float* __restrict__ out)
{
  const int o = blockIdx.x, b = blockIdx.y, tid = threadIdx.x;
  __shared__ float swm[4608];
  __shared__ float red[4];
  const float gain = 0.014731391f;
  const float* wo = w + (size_t)o * 4608;
  const float* st = style + (size_t)b * 512;
  float ss = 0.f;
#pragma unroll
  for (int j = 0; j < 18; ++j) {
    int idx = j * 256 + tid;
    float v = wo[idx] * gain * st[idx / 9];
    swm[idx] = v;
    ss += v * v;
  }
#pragma unroll
  for (int off = 32; off > 0; off >>= 1) ss += __shfl_down(ss, off, 64);
  if ((tid & 63) == 0) red[tid >> 6] = ss;
  __syncthreads();
  const float sinv = rsqrtf(red[0] + red[1] + red[2] + red[3] + 1e-8f);

  const int y = tid >> 2, x0 = (tid & 3) * 16;
  float acc[16];
#pragma unroll
  for (int i = 0; i < 16; ++i) acc[i] = 0.f;
  const float* fb = fm + (size_t)b * 512 * 4096;
  for (int ci = 0; ci < 512; ++ci) {
    const float* fc = fb + (size_t)ci * 4096;
    const float* wr = swm + ci * 9;
#pragma unroll
    for (int ky = 0; ky < 3; ++ky) {
      int yy = y + ky - 1;
      if (yy < 0 || yy > 63) continue;
      const float* frow = fc + yy * 64;
#pragma unroll
      for (int kx = 0; kx < 3; ++kx) {
        float wv = wr[ky * 3 + kx];
#pragma unroll
        for (int i = 0; i < 16; ++i) {
          int xx = x0 + i + kx - 1;
          float xv = (xx >= 0 && xx < 64) ? frow[xx] : 0.f;
          acc[i] += wv * xv;
        }
      }
    }
  }
  float* op = out + ((size_t)b * 512 + o) * 4096 + y * 64 + x0;
#pragma unroll
  for (int i = 0; i < 16; ++i) op[i] = acc[i] * sinv;
}

extern "C" void kernel_launch(void* const* d_in, const int* in_sizes, int n_in,
                              void* d_out, int out_size, void* d_ws, size_t ws_size,
                              hipStream_t stream) {
  const float* fm = (const float*)d_in[0];     // (8,512,64,64) fp32
  const float* style = (const float*)d_in[1];  // (8,512) fp32
  const float* w = (const float*)d_in[2];      // (512,512,3,3) fp32
  float* out = (float*)d_out;                  // (8,512,64,64) fp32

  if (ws_size < XT_PB + WM_PB) {               // workspace too small: direct path
    conv_direct<<<dim3(512, 8), 256, 0, stream>>>(fm, style, w, out);
    return;
  }
  int nb = 8;
  while (nb > 1 && (size_t)nb * (XT_PB + WM_PB) > ws_size) nb >>= 1;

  u16* xt = (u16*)d_ws;
  u16* wmod = (u16*)((char*)d_ws + (size_t)nb * XT_PB);

  for (int b0 = 0; b0 < 8; b0 += nb) {
    prep_fused<<<dim3(1536 * nb), 256, 0, stream>>>(fm, w, style, xt, wmod, b0);
    conv_mfma<<<dim3(128 * nb), 128, 0, stream>>>(wmod, xt, out, b0, nb);
  }
}